// Round 16
// baseline (183.684 us; speedup 1.0000x reference)
//
#include <hip/hip_runtime.h>

#define Bn 32
#define Nn 24564
#define MAXB 200
#define NBIN 2048
#define CH 2048
#define NCHK 4
#define CHK_PRE 3
#define CHTOT (NCHK * CH)
#define CHPRE (CHK_PRE * CH)
#define INVK 0xFFFFFFFFu
#define NITER 24

typedef unsigned long long u64;
typedef unsigned int u32;

// -------- accurate double exp (rel err ~6e-15) -- bit-stable since R2 --------
__device__ inline double fast_exp_d(double x) {
  const double LOG2E = 1.4426950408889634074;
  const double LN2   = 0.69314718055994530942;
  double t = x * LOG2E;
  double fi = floor(t + 0.5);
  double f = (t - fi) * LN2;
  double p = 2.505210838544172e-8;
  p = p * f + 2.755731922398589e-7;
  p = p * f + 2.7557319223985893e-6;
  p = p * f + 2.48015873015873e-5;
  p = p * f + 1.984126984126984e-4;
  p = p * f + 1.3888888888888889e-3;
  p = p * f + 8.333333333333333e-3;
  p = p * f + 4.1666666666666664e-2;
  p = p * f + 1.6666666666666666e-1;
  p = p * f + 0.5;
  p = p * f + 1.0;
  p = p * f + 1.0;
  long long e = (long long)fi;
  return p * __longlong_as_double((e + 1023LL) << 52);
}

__device__ inline double clip01(double v) {
  return v < 0.0 ? 0.0 : (v > 1.0 ? 1.0 : v);
}

// ============================================================
// z1: f32 scoring, direct global loads (R14-proven, ~38us, HBM roofline)
// ============================================================
__global__ __launch_bounds__(256) void z1_score(const float* __restrict__ logits,
                                                u32* __restrict__ keyA) {
  const int tid = threadIdx.x;
  const int bx = blockIdx.x;
  const int b = bx / 384;
  const int n0 = (bx % 384) << 6;
  const int g = tid >> 2, s = tid & 3;
  const int n = n0 + g;
  if (n >= Nn) return;
  const float* row = logits + ((size_t)b * Nn + n) * 85;

  float rv[21];
  float mx = -1e30f; int ai = 1000;
  #pragma unroll
  for (int q = 0; q < 21; ++q) {
    int c = s + 4 * q;
    float v = (c < 81) ? row[4 + c] : -1e30f;
    rv[q] = v;
    if (c < 81 && v > mx) { mx = v; ai = c; }
  }
  #pragma unroll
  for (int d = 1; d <= 2; d <<= 1) {
    float om = __shfl_xor(mx, d);
    int oi = __shfl_xor(ai, d);
    if (om > mx || (om == mx && oi < ai)) { mx = om; ai = oi; }
  }
  float sum = 0.f;
  #pragma unroll
  for (int q = 0; q < 21; ++q) {
    if (s + 4 * q < 81) sum += __expf(rv[q] - mx);
  }
  sum += __shfl_xor(sum, 1);
  sum += __shfl_xor(sum, 2);
  if (s == 0) {
    float sc = 1.0f / sum;
    u32 kv = INVK;
    if (ai != 0 && sc >= 0.00985f) kv = ~__float_as_uint(sc);  // margin; exact recheck later
    keyA[(size_t)b * Nn + n] = kv;
  }
}

// ============================================================
// z3: per-image cut+compact, register-prefetched keys (verbatim R15)
// ============================================================
__global__ __launch_bounds__(1024) void z3_cutcompact(const u32* __restrict__ keyA,
                                                      int* __restrict__ chunkCntG,
                                                      int* __restrict__ clist) {
  __shared__ int hist[NBIN];
  __shared__ int chunkIdL[NBIN];
  __shared__ int wsum[16];
  __shared__ int sBinHi;
  __shared__ int sCnt[NCHK];
  const int b = blockIdx.x;
  const int tid = threadIdx.x;
  const int lane = tid & 63, wid = tid >> 6;
  const u32* kb = keyA + (size_t)b * Nn;

  u32 kvreg[NITER];
  #pragma unroll
  for (int it = 0; it < NITER; ++it) {
    int i = it * 1024 + tid;
    kvreg[it] = (i < Nn) ? kb[i] : INVK;
  }

  for (int i = tid; i < NBIN; i += 1024) hist[i] = 0;
  chunkIdL[2 * tid] = 255;
  chunkIdL[2 * tid + 1] = 255;
  if (tid < NCHK) sCnt[tid] = 0;
  __syncthreads();

  #pragma unroll
  for (int it = 0; it < NITER; ++it) {
    u32 bin = (kvreg[it] - 0xC0000000u) >> 15;
    if (bin < NBIN) atomicAdd(&hist[bin], 1);
  }
  __syncthreads();

  int h0 = hist[2 * tid], h1 = hist[2 * tid + 1];
  int v = h0 + h1;
  int iv = v;
  #pragma unroll
  for (int d = 1; d < 64; d <<= 1) {
    int t = __shfl_up(iv, d);
    if (lane >= d) iv += t;
  }
  if (lane == 63) wsum[wid] = iv;
  __syncthreads();
  if (tid < 16) {
    int w = wsum[tid];
    #pragma unroll
    for (int d = 1; d < 16; d <<= 1) {
      int t = __shfl_up(w, d);
      if ((int)tid >= d) w += t;
    }
    wsum[tid] = w;
  }
  __syncthreads();
  int excl = iv - v + (wid > 0 ? wsum[wid - 1] : 0);
  hist[2 * tid] = excl + h0;
  hist[2 * tid + 1] = excl + h0 + h1;
  __syncthreads();

  int binLo = -1, cumBase = 0;
  for (int c = 0; c < NCHK; ++c) {
    if (tid == 0) sBinHi = binLo;
    __syncthreads();
    const int limit = cumBase + CH;
    int loc = -1;
    if (hist[2 * tid] <= limit) loc = 2 * tid;
    if (hist[2 * tid + 1] <= limit) loc = 2 * tid + 1;
    if (loc > binLo) atomicMax(&sBinHi, loc);
    __syncthreads();
    int binHi = sBinHi;
    if (binHi == binLo) binHi = binLo + 1;   // oversized-single-bin fallback
    if (2 * tid > binLo && 2 * tid <= binHi) chunkIdL[2 * tid] = c;
    if (2 * tid + 1 > binLo && 2 * tid + 1 <= binHi) chunkIdL[2 * tid + 1] = c;
    cumBase = hist[(binHi < NBIN ? binHi : NBIN - 1)];
    binLo = binHi;
    __syncthreads();
  }

  #pragma unroll 1
  for (int it = 0; it < NITER; ++it) {
    int i = it * 1024 + tid;
    int c = 255;
    u32 bin = (kvreg[it] - 0xC0000000u) >> 15;
    if (i < Nn && bin < NBIN) c = chunkIdL[bin];
    #pragma unroll
    for (int cc = 0; cc < NCHK; ++cc) {
      bool pred = (c == cc);
      u64 m = __ballot(pred);
      if (m) {
        int base = 0;
        if (lane == 0) base = atomicAdd(&sCnt[cc], (int)__popcll(m));
        base = __shfl(base, 0);
        if (pred) {
          int off = (int)__popcll(m & ((1ULL << lane) - 1ULL));
          int p = base + off;
          if (p < CH) clist[b * CHTOT + cc * CH + p] = i;
        }
      }
    }
  }
  __syncthreads();
  if (tid < NCHK) chunkCntG[b * NCHK + tid] = sCnt[tid];
}

// ============================================================
// z4: full-grid exact f64 rescore of chunks 0..2 + 256-presort (verbatim R15)
// ============================================================
__global__ __launch_bounds__(256) void z4_rescore(const float* __restrict__ logits,
                                                  const float* __restrict__ anchors,
                                                  const int* __restrict__ clist,
                                                  const int* __restrict__ chunkCntG,
                                                  double* __restrict__ boxesd,
                                                  int* __restrict__ clsd,
                                                  u64* __restrict__ ekeysG) {
  __shared__ u64 ekseg[256];
  const int tid = threadIdx.x;
  const int bx = blockIdx.x;
  const int b = bx / (CHK_PRE * 8);
  const int blk = bx % (CHK_PRE * 8);
  const int c = blk >> 3;
  const int seg = blk & 7;
  int cnt = chunkCntG[b * NCHK + c];
  cnt = cnt > CH ? CH : cnt;
  const int g = tid >> 2, s = tid & 3;

  #pragma unroll 1
  for (int pass = 0; pass < 4; ++pass) {
    const int slot = seg * 256 + pass * 64 + g;
    u64 K = ~0ULL;
    if (slot < cnt) {
      const int n = clist[b * CHTOT + c * CH + slot];
      const float* row = logits + ((size_t)b * Nn + n) * 85;
      float rv[21];
      float mx = -1e30f; int ai = 1000;
      #pragma unroll
      for (int q = 0; q < 21; ++q) {
        int cc = s + 4 * q;
        float vv = (cc < 81) ? row[4 + cc] : -1e30f;
        rv[q] = vv;
        if (cc < 81 && vv > mx) { mx = vv; ai = cc; }
      }
      #pragma unroll
      for (int d = 1; d <= 2; d <<= 1) {
        float om = __shfl_xor(mx, d);
        int oi = __shfl_xor(ai, d);
        if (om > mx || (om == mx && oi < ai)) { mx = om; ai = oi; }
      }
      double sum = 0.0;
      #pragma unroll
      for (int q = 0; q < 21; ++q) {
        if (s + 4 * q < 81) sum += fast_exp_d((double)rv[q] - (double)mx);
      }
      sum += __shfl_xor(sum, 1);
      sum += __shfl_xor(sum, 2);
      if (s == 0) {
        double score = 1.0 / sum;
        if (ai != 0 && score >= 0.01) {
          float4 a4 = reinterpret_cast<const float4*>(anchors)[n];
          double ax1 = a4.x, ay1 = a4.y, ax2 = a4.z, ay2 = a4.w;
          double cx = (ax2 + ax1) * 0.5, cy = (ay2 + ay1) * 0.5;
          double ww = ax2 - ax1, hh = ay2 - ay1;
          double ctrx = (double)row[0] * ww + cx;
          double ctry = (double)row[1] * hh + cy;
          double szx = fast_exp_d((double)row[2]) * ww;
          double szy = fast_exp_d((double)row[3]) * hh;
          double* bp = boxesd + (size_t)(b * Nn + n) * 4;
          bp[0] = clip01(ctrx - szx * 0.5);
          bp[1] = clip01(ctry - szy * 0.5);
          bp[2] = clip01(ctrx + szx * 0.5);
          bp[3] = clip01(ctry + szy * 0.5);
          clsd[b * Nn + n] = ai;
          u64 sb2 = (u64)__double_as_longlong(score);
          u64 e4 = (sb2 >> 52) - 1015ULL;
          u64 mant45 = (sb2 & ((1ULL << 52) - 1)) >> 7;
          u64 flip = (~((e4 << 45) | mant45)) & ((1ULL << 49) - 1);
          K = (flip << 15) | (u64)n;
        }
      }
    }
    if (s == 0) ekseg[pass * 64 + g] = K;
  }
  __syncthreads();

  for (int k = 2; k <= 256; k <<= 1) {
    for (int j = k >> 1; j >= 1; j >>= 1) {
      if (tid < 128) {
        int l = ((tid & ~(j - 1)) << 1) | (tid & (j - 1));
        int r = l | j;
        bool up = ((l & k) == 0);
        u64 a = ekseg[l], bv = ekseg[r];
        if ((a > bv) == up) { ekseg[l] = bv; ekseg[r] = a; }
      }
      __syncthreads();
    }
  }
  u64* dstp = ekeysG + (size_t)b * CHPRE + c * CH + seg * 256;
  for (int i = tid; i < 256; i += 256) dstp[i] = ekseg[i];
}

// ============================================================
// z5: per-image: chunk loop {merge (or inline path) -> cbox-to-LDS ->
// 128-wide multi-wave NMS with 128-bit kill-masks} -> outputs
// ============================================================
__global__ __launch_bounds__(1024) void z5_sortnms(const float* __restrict__ logits,
                                                   const float* __restrict__ anchors,
                                                   const u64* __restrict__ ekeysG,
                                                   const int* __restrict__ chunkCntG,
                                                   const int* __restrict__ clist,
                                                   double* __restrict__ boxesd,
                                                   int* __restrict__ clsd,
                                                   float* __restrict__ out) {
  __shared__ u64 ek[CH];
  __shared__ double cbX1[CH], cbY1[CH], cbX2[CH], cbY2[CH];  // SoA, conflict-free
  __shared__ u64 awv[16];
  __shared__ u64 killmLo[128], killmHi[128];
  __shared__ double selBox[MAXB][4];
  __shared__ double selArea[MAXB];
  __shared__ float selScore[MAXB];
  __shared__ int selIdx[MAXB];
  __shared__ int sS;
  const int b = blockIdx.x;
  const int tid = threadIdx.x;
  const int lane = tid & 63, wid = tid >> 6;
  const double THR = 0.45;
  if (tid == 0) sS = 0;
  __syncthreads();

  for (int c = 0; c < NCHK; ++c) {
    if (sS >= MAXB) break;
    int cnt = chunkCntG[b * NCHK + c];
    cnt = cnt > CH ? CH : cnt;
    if (cnt == 0) break;

    if (c < CHK_PRE) {
      for (int i = tid; i < CH; i += 1024) ek[i] = ekeysG[(size_t)b * CHPRE + c * CH + i];
      __syncthreads();
      for (int L = 256; L <= 1024; L <<= 1) {
        int pair = tid / L, i = tid % L;
        int base = pair * 2 * L;
        int l = base + i, r = base + 2 * L - 1 - i;
        u64 a = ek[l], bv = ek[r];
        if (a > bv) { ek[l] = bv; ek[r] = a; }
        __syncthreads();
        for (int j = L >> 1; j >= 1; j >>= 1) {
          int ll = ((tid & ~(j - 1)) << 1) | (tid & (j - 1));
          int rr = ll | j;
          u64 x = ek[ll], y = ek[rr];
          if (x > y) { ek[ll] = y; ek[rr] = x; }
          __syncthreads();
        }
      }
    } else {
      // inline exact rescore (R6-proven, rare path)
      for (int i = tid; i < CH; i += 1024) ek[i] = ~0ULL;
      __syncthreads();
      const int g = tid >> 2, s4 = tid & 3;
      #pragma unroll 1
      for (int pass = 0; pass < CH / 256; ++pass) {
        int slot = pass * 256 + g;
        if (slot < cnt) {
          const int n = clist[b * CHTOT + c * CH + slot];
          const float* row = logits + ((size_t)b * Nn + n) * 85;
          float rv[21];
          float mx = -1e30f; int ai = 1000;
          #pragma unroll
          for (int q = 0; q < 21; ++q) {
            int cc = s4 + 4 * q;
            float vv = (cc < 81) ? row[4 + cc] : -1e30f;
            rv[q] = vv;
            if (cc < 81 && vv > mx) { mx = vv; ai = cc; }
          }
          #pragma unroll
          for (int d = 1; d <= 2; d <<= 1) {
            float om = __shfl_xor(mx, d);
            int oi = __shfl_xor(ai, d);
            if (om > mx || (om == mx && oi < ai)) { mx = om; ai = oi; }
          }
          double sum = 0.0;
          #pragma unroll
          for (int q = 0; q < 21; ++q) {
            if (s4 + 4 * q < 81) sum += fast_exp_d((double)rv[q] - (double)mx);
          }
          sum += __shfl_xor(sum, 1);
          sum += __shfl_xor(sum, 2);
          if (s4 == 0) {
            u64 K = ~0ULL;
            double score = 1.0 / sum;
            if (ai != 0 && score >= 0.01) {
              float4 a4 = reinterpret_cast<const float4*>(anchors)[n];
              double ax1 = a4.x, ay1 = a4.y, ax2 = a4.z, ay2 = a4.w;
              double cx = (ax2 + ax1) * 0.5, cy = (ay2 + ay1) * 0.5;
              double ww = ax2 - ax1, hh = ay2 - ay1;
              double ctrx = (double)row[0] * ww + cx;
              double ctry = (double)row[1] * hh + cy;
              double szx = fast_exp_d((double)row[2]) * ww;
              double szy = fast_exp_d((double)row[3]) * hh;
              double* bp = boxesd + (size_t)(b * Nn + n) * 4;
              bp[0] = clip01(ctrx - szx * 0.5);
              bp[1] = clip01(ctry - szy * 0.5);
              bp[2] = clip01(ctrx + szx * 0.5);
              bp[3] = clip01(ctry + szy * 0.5);
              clsd[b * Nn + n] = ai;
              u64 sb2 = (u64)__double_as_longlong(score);
              u64 e4 = (sb2 >> 52) - 1015ULL;
              u64 mant45 = (sb2 & ((1ULL << 52) - 1)) >> 7;
              u64 flip = (~((e4 << 45) | mant45)) & ((1ULL << 49) - 1);
              K = (flip << 15) | (u64)n;
            }
            ek[slot] = K;
          }
        }
      }
      __syncthreads();
      int P2 = 64;
      while (P2 < cnt) P2 <<= 1;
      for (int k = 2; k <= P2; k <<= 1) {
        for (int j = k >> 1; j >= 1; j >>= 1) {
          if (tid < (P2 >> 1)) {
            int l = ((tid & ~(j - 1)) << 1) | (tid & (j - 1));
            int r = l | j;
            bool up = ((l & k) == 0);
            u64 a = ek[l], bbv = ek[r];
            if ((a > bbv) == up) { ek[l] = bbv; ek[r] = a; }
          }
          __syncthreads();
        }
      }
    }

    // ---- one-time per-chunk box load into LDS (sorted order, via key's anchor) ----
    for (int i = tid; i < CH; i += 1024) {
      u64 Kc = ek[i];
      double x1 = 0.0, y1 = 0.0, x2 = 0.0, y2 = 0.0;
      if (Kc != ~0ULL) {
        const double* bp = boxesd + (size_t)(b * Nn + (int)(Kc & 0x7FFF)) * 4;
        x1 = bp[0]; y1 = bp[1]; x2 = bp[2]; y2 = bp[3];
      }
      cbX1[i] = x1; cbY1[i] = y1; cbX2[i] = x2; cbY2[i] = y2;
    }
    __syncthreads();

    // ---- multi-wave NMS, 128-wide batches, 128-bit kill-masks ----
    const int half = wid >> 3;          // 0: candidates 0-63, 1: 64-127
    const int wsub = wid & 7;
    int pos = 0;
    for (;;) {
      int S = sS;
      if (S >= MAXB || pos >= CH) break;
      bool anyLo = __any(ek[pos + lane] != ~0ULL);   // uniform (sorted: lo empty => hi empty)
      if (!anyLo) break;

      const int cc = half * 64 + lane;
      double cx1 = cbX1[pos + cc], cy1 = cbY1[pos + cc];
      double cx2 = cbX2[pos + cc], cy2 = cbY2[pos + cc];
      double carea = (cx2 - cx1) * (cy2 - cy1);

      // phase 1: vs committed selections, slices k == wsub (mod 8)
      bool aliveL = true;
      for (int k = wsub; k < S; k += 8) {
        double ltx = fmax(selBox[k][0], cx1), lty = fmax(selBox[k][1], cy1);
        double rbx = fmin(selBox[k][2], cx2), rby = fmin(selBox[k][3], cy2);
        double w = rbx - ltx; w = w < 0 ? 0 : w;
        double h = rby - lty; h = h < 0 ? 0 : h;
        double inter = w * h;
        double denom = selArea[k] + carea - inter + 1e-9;
        if (inter > THR * denom) aliveL = false;
      }
      u64 aw = __ballot(aliveL);
      if (lane == 0) awv[wid] = aw;

      // lane's lo/hi boxes for phase 1.5 ballots
      double lx1 = cbX1[pos + lane], ly1 = cbY1[pos + lane];
      double lx2 = cbX2[pos + lane], ly2 = cbY2[pos + lane];
      double lar = (lx2 - lx1) * (ly2 - ly1);
      double hx1 = cbX1[pos + 64 + lane], hy1 = cbY1[pos + 64 + lane];
      double hx2 = cbX2[pos + 64 + lane], hy2 = cbY2[pos + 64 + lane];
      double har = (hx2 - hx1) * (hy2 - hy1);

      // phase 1.5: wave wid owns j = 8*wid .. 8*wid+7
      #pragma unroll
      for (int q = 0; q < 8; ++q) {
        int j = (wid << 3) | q;
        double jx1 = cbX1[pos + j], jy1 = cbY1[pos + j];
        double jx2 = cbX2[pos + j], jy2 = cbY2[pos + j];
        double jar = (jx2 - jx1) * (jy2 - jy1);
        // vs lo candidate (lane)
        double ltx = fmax(jx1, lx1), lty = fmax(jy1, ly1);
        double rbx = fmin(jx2, lx2), rby = fmin(jy2, ly2);
        double w = rbx - ltx; w = w < 0 ? 0 : w;
        double h = rby - lty; h = h < 0 ? 0 : h;
        double inter = w * h;
        double denom = jar + lar - inter + 1e-9;
        u64 kmLo = __ballot(inter > THR * denom);
        // vs hi candidate (64+lane)
        ltx = fmax(jx1, hx1); lty = fmax(jy1, hy1);
        rbx = fmin(jx2, hx2); rby = fmin(jy2, hy2);
        w = rbx - ltx; w = w < 0 ? 0 : w;
        h = rby - lty; h = h < 0 ? 0 : h;
        inter = w * h;
        denom = jar + har - inter + 1e-9;
        u64 kmHi = __ballot(inter > THR * denom);
        if (lane == 0) { killmLo[j] = kmLo; killmHi[j] = kmHi; }
      }
      __syncthreads();

      // phase 2: wave 0, sequential mask propagation (decisions bit-identical)
      if (tid < 64) {
        u64 m0 = __ballot(ek[pos + lane] != ~0ULL);
        u64 m1 = __ballot(ek[pos + 64 + lane] != ~0ULL);
        #pragma unroll
        for (int w = 0; w < 8; ++w)  m0 &= awv[w];
        #pragma unroll
        for (int w = 8; w < 16; ++w) m1 &= awv[w];
        int Sl = S;
        while ((m0 | m1) != 0 && Sl < MAXB) {
          int j = m0 ? (__ffsll((unsigned long long)m0) - 1)
                     : (64 + __ffsll((unsigned long long)m1) - 1);
          if (lane == 0) {
            double jx1 = cbX1[pos + j], jy1 = cbY1[pos + j];
            double jx2 = cbX2[pos + j], jy2 = cbY2[pos + j];
            u64 Kj = ek[pos + j];
            u64 key49 = (~(Kj >> 15)) & ((1ULL << 49) - 1);
            u64 e = (key49 >> 45) + 1015ULL;
            u64 mant = (key49 & ((1ULL << 45) - 1)) << 7;
            selBox[Sl][0] = jx1; selBox[Sl][1] = jy1;
            selBox[Sl][2] = jx2; selBox[Sl][3] = jy2;
            selArea[Sl] = (jx2 - jx1) * (jy2 - jy1);
            selScore[Sl] = (float)__longlong_as_double((long long)((e << 52) | mant));
            selIdx[Sl] = (int)(Kj & 0x7FFF);
          }
          Sl++;
          if (j < 64) m0 &= ~(1ULL << j); else m1 &= ~(1ULL << (j - 64));
          m0 &= ~killmLo[j];
          m1 &= ~killmHi[j];
        }
        if (lane == 0) sS = Sl;
      }
      __syncthreads();
      pos += 128;
    }
    __syncthreads();
  }

  // --- outputs (whole buffer read as f32 by harness) ---
  const int S = sS;
  float* det_boxes = out;
  float* det_classes = out + Bn * MAXB * 4;
  float* det_scores = out + Bn * MAXB * 4 + Bn * MAXB;
  float* det_num = out + Bn * MAXB * 4 + 2 * Bn * MAXB;
  for (int k = tid; k < MAXB; k += 1024) {
    int o = b * MAXB + k;
    if (k < S) {
      det_boxes[o * 4 + 0] = (float)selBox[k][0];
      det_boxes[o * 4 + 1] = (float)selBox[k][1];
      det_boxes[o * 4 + 2] = (float)selBox[k][2];
      det_boxes[o * 4 + 3] = (float)selBox[k][3];
      det_classes[o] = (float)clsd[b * Nn + selIdx[k]];
      det_scores[o] = selScore[k];
    } else {
      det_boxes[o * 4 + 0] = 0.f; det_boxes[o * 4 + 1] = 0.f;
      det_boxes[o * 4 + 2] = 0.f; det_boxes[o * 4 + 3] = 0.f;
      det_classes[o] = 0.f;
      det_scores[o] = 0.f;
    }
  }
  if (tid == 0) det_num[b] = (float)S;
}

// ============================================================
extern "C" void kernel_launch(void* const* d_in, const int* in_sizes, int n_in,
                              void* d_out, int out_size, void* d_ws, size_t ws_size,
                              hipStream_t stream) {
  const float* logits = (const float*)d_in[0];
  const float* anchors = (const float*)d_in[1];
  float* out = (float*)d_out;
  char* ws = (char*)d_ws;

  double* boxesd = (double*)ws;
  size_t off = (size_t)Bn * Nn * 4 * sizeof(double);
  int* clsd    = (int*)(ws + off);  off += (size_t)Bn * Nn * sizeof(int);
  u32* keyA    = (u32*)(ws + off);  off += (size_t)Bn * Nn * sizeof(u32);
  int* chunkCnt= (int*)(ws + off);  off += (size_t)Bn * NCHK * sizeof(int);
  int* clist   = (int*)(ws + off);  off += (size_t)Bn * CHTOT * sizeof(int);
  u64* ekeysG  = (u64*)(ws + off);

  z1_score     <<<dim3(Bn * 384),        dim3(256),  0, stream>>>(logits, keyA);
  z3_cutcompact<<<dim3(Bn),              dim3(1024), 0, stream>>>(keyA, chunkCnt, clist);
  z4_rescore   <<<dim3(Bn * CHK_PRE * 8),dim3(256),  0, stream>>>(logits, anchors, clist,
                                                                  chunkCnt, boxesd, clsd, ekeysG);
  z5_sortnms   <<<dim3(Bn),              dim3(1024), 0, stream>>>(logits, anchors, ekeysG,
                                                                  chunkCnt, clist, boxesd,
                                                                  clsd, out);
}

// Round 17
// 154.071 us; speedup vs baseline: 1.1922x; 1.1922x over previous
//
#include <hip/hip_runtime.h>

#define Bn 32
#define Nn 24564
#define MAXB 200
#define NBIN 2048
#define CH 2048
#define NCHK 4
#define CHK_PRE 3
#define CHTOT (NCHK * CH)
#define CHPRE (CHK_PRE * CH)
#define INVK 0xFFFFFFFFu
#define NITER 24

typedef unsigned long long u64;
typedef unsigned int u32;

// -------- accurate double exp (rel err ~6e-15) -- bit-stable since R2 --------
__device__ inline double fast_exp_d(double x) {
  const double LOG2E = 1.4426950408889634074;
  const double LN2   = 0.69314718055994530942;
  double t = x * LOG2E;
  double fi = floor(t + 0.5);
  double f = (t - fi) * LN2;
  double p = 2.505210838544172e-8;
  p = p * f + 2.755731922398589e-7;
  p = p * f + 2.7557319223985893e-6;
  p = p * f + 2.48015873015873e-5;
  p = p * f + 1.984126984126984e-4;
  p = p * f + 1.3888888888888889e-3;
  p = p * f + 8.333333333333333e-3;
  p = p * f + 4.1666666666666664e-2;
  p = p * f + 1.6666666666666666e-1;
  p = p * f + 0.5;
  p = p * f + 1.0;
  p = p * f + 1.0;
  long long e = (long long)fi;
  return p * __longlong_as_double((e + 1023LL) << 52);
}

__device__ inline double clip01(double v) {
  return v < 0.0 ? 0.0 : (v > 1.0 ? 1.0 : v);
}

// ============================================================
// z1: f32 scoring, direct global loads (R14-proven, ~38us, HBM roofline)
// ============================================================
__global__ __launch_bounds__(256) void z1_score(const float* __restrict__ logits,
                                                u32* __restrict__ keyA) {
  const int tid = threadIdx.x;
  const int bx = blockIdx.x;
  const int b = bx / 384;
  const int n0 = (bx % 384) << 6;
  const int g = tid >> 2, s = tid & 3;
  const int n = n0 + g;
  if (n >= Nn) return;
  const float* row = logits + ((size_t)b * Nn + n) * 85;

  float rv[21];
  float mx = -1e30f; int ai = 1000;
  #pragma unroll
  for (int q = 0; q < 21; ++q) {
    int c = s + 4 * q;
    float v = (c < 81) ? row[4 + c] : -1e30f;
    rv[q] = v;
    if (c < 81 && v > mx) { mx = v; ai = c; }
  }
  #pragma unroll
  for (int d = 1; d <= 2; d <<= 1) {
    float om = __shfl_xor(mx, d);
    int oi = __shfl_xor(ai, d);
    if (om > mx || (om == mx && oi < ai)) { mx = om; ai = oi; }
  }
  float sum = 0.f;
  #pragma unroll
  for (int q = 0; q < 21; ++q) {
    if (s + 4 * q < 81) sum += __expf(rv[q] - mx);
  }
  sum += __shfl_xor(sum, 1);
  sum += __shfl_xor(sum, 2);
  if (s == 0) {
    float sc = 1.0f / sum;
    u32 kv = INVK;
    if (ai != 0 && sc >= 0.00985f) kv = ~__float_as_uint(sc);  // margin; exact recheck later
    keyA[(size_t)b * Nn + n] = kv;
  }
}

// ============================================================
// z3: per-image cut+compact, register-prefetched keys (verbatim R15)
// ============================================================
__global__ __launch_bounds__(1024) void z3_cutcompact(const u32* __restrict__ keyA,
                                                      int* __restrict__ chunkCntG,
                                                      int* __restrict__ clist) {
  __shared__ int hist[NBIN];
  __shared__ int chunkIdL[NBIN];
  __shared__ int wsum[16];
  __shared__ int sBinHi;
  __shared__ int sCnt[NCHK];
  const int b = blockIdx.x;
  const int tid = threadIdx.x;
  const int lane = tid & 63, wid = tid >> 6;
  const u32* kb = keyA + (size_t)b * Nn;

  u32 kvreg[NITER];
  #pragma unroll
  for (int it = 0; it < NITER; ++it) {
    int i = it * 1024 + tid;
    kvreg[it] = (i < Nn) ? kb[i] : INVK;
  }

  for (int i = tid; i < NBIN; i += 1024) hist[i] = 0;
  chunkIdL[2 * tid] = 255;
  chunkIdL[2 * tid + 1] = 255;
  if (tid < NCHK) sCnt[tid] = 0;
  __syncthreads();

  #pragma unroll
  for (int it = 0; it < NITER; ++it) {
    u32 bin = (kvreg[it] - 0xC0000000u) >> 15;
    if (bin < NBIN) atomicAdd(&hist[bin], 1);
  }
  __syncthreads();

  int h0 = hist[2 * tid], h1 = hist[2 * tid + 1];
  int v = h0 + h1;
  int iv = v;
  #pragma unroll
  for (int d = 1; d < 64; d <<= 1) {
    int t = __shfl_up(iv, d);
    if (lane >= d) iv += t;
  }
  if (lane == 63) wsum[wid] = iv;
  __syncthreads();
  if (tid < 16) {
    int w = wsum[tid];
    #pragma unroll
    for (int d = 1; d < 16; d <<= 1) {
      int t = __shfl_up(w, d);
      if ((int)tid >= d) w += t;
    }
    wsum[tid] = w;
  }
  __syncthreads();
  int excl = iv - v + (wid > 0 ? wsum[wid - 1] : 0);
  hist[2 * tid] = excl + h0;
  hist[2 * tid + 1] = excl + h0 + h1;
  __syncthreads();

  int binLo = -1, cumBase = 0;
  for (int c = 0; c < NCHK; ++c) {
    if (tid == 0) sBinHi = binLo;
    __syncthreads();
    const int limit = cumBase + CH;
    int loc = -1;
    if (hist[2 * tid] <= limit) loc = 2 * tid;
    if (hist[2 * tid + 1] <= limit) loc = 2 * tid + 1;
    if (loc > binLo) atomicMax(&sBinHi, loc);
    __syncthreads();
    int binHi = sBinHi;
    if (binHi == binLo) binHi = binLo + 1;   // oversized-single-bin fallback
    if (2 * tid > binLo && 2 * tid <= binHi) chunkIdL[2 * tid] = c;
    if (2 * tid + 1 > binLo && 2 * tid + 1 <= binHi) chunkIdL[2 * tid + 1] = c;
    cumBase = hist[(binHi < NBIN ? binHi : NBIN - 1)];
    binLo = binHi;
    __syncthreads();
  }

  #pragma unroll 1
  for (int it = 0; it < NITER; ++it) {
    int i = it * 1024 + tid;
    int c = 255;
    u32 bin = (kvreg[it] - 0xC0000000u) >> 15;
    if (i < Nn && bin < NBIN) c = chunkIdL[bin];
    #pragma unroll
    for (int cc = 0; cc < NCHK; ++cc) {
      bool pred = (c == cc);
      u64 m = __ballot(pred);
      if (m) {
        int base = 0;
        if (lane == 0) base = atomicAdd(&sCnt[cc], (int)__popcll(m));
        base = __shfl(base, 0);
        if (pred) {
          int off = (int)__popcll(m & ((1ULL << lane) - 1ULL));
          int p = base + off;
          if (p < CH) clist[b * CHTOT + cc * CH + p] = i;
        }
      }
    }
  }
  __syncthreads();
  if (tid < NCHK) chunkCntG[b * NCHK + tid] = sCnt[tid];
}

// ============================================================
// z4: full-grid exact f64 rescore of chunks 0..2 + 256-presort (verbatim R15)
// ============================================================
__global__ __launch_bounds__(256) void z4_rescore(const float* __restrict__ logits,
                                                  const float* __restrict__ anchors,
                                                  const int* __restrict__ clist,
                                                  const int* __restrict__ chunkCntG,
                                                  double* __restrict__ boxesd,
                                                  int* __restrict__ clsd,
                                                  u64* __restrict__ ekeysG) {
  __shared__ u64 ekseg[256];
  const int tid = threadIdx.x;
  const int bx = blockIdx.x;
  const int b = bx / (CHK_PRE * 8);
  const int blk = bx % (CHK_PRE * 8);
  const int c = blk >> 3;
  const int seg = blk & 7;
  int cnt = chunkCntG[b * NCHK + c];
  cnt = cnt > CH ? CH : cnt;
  const int g = tid >> 2, s = tid & 3;

  #pragma unroll 1
  for (int pass = 0; pass < 4; ++pass) {
    const int slot = seg * 256 + pass * 64 + g;
    u64 K = ~0ULL;
    if (slot < cnt) {
      const int n = clist[b * CHTOT + c * CH + slot];
      const float* row = logits + ((size_t)b * Nn + n) * 85;
      float rv[21];
      float mx = -1e30f; int ai = 1000;
      #pragma unroll
      for (int q = 0; q < 21; ++q) {
        int cc = s + 4 * q;
        float vv = (cc < 81) ? row[4 + cc] : -1e30f;
        rv[q] = vv;
        if (cc < 81 && vv > mx) { mx = vv; ai = cc; }
      }
      #pragma unroll
      for (int d = 1; d <= 2; d <<= 1) {
        float om = __shfl_xor(mx, d);
        int oi = __shfl_xor(ai, d);
        if (om > mx || (om == mx && oi < ai)) { mx = om; ai = oi; }
      }
      double sum = 0.0;
      #pragma unroll
      for (int q = 0; q < 21; ++q) {
        if (s + 4 * q < 81) sum += fast_exp_d((double)rv[q] - (double)mx);
      }
      sum += __shfl_xor(sum, 1);
      sum += __shfl_xor(sum, 2);
      if (s == 0) {
        double score = 1.0 / sum;
        if (ai != 0 && score >= 0.01) {
          float4 a4 = reinterpret_cast<const float4*>(anchors)[n];
          double ax1 = a4.x, ay1 = a4.y, ax2 = a4.z, ay2 = a4.w;
          double cx = (ax2 + ax1) * 0.5, cy = (ay2 + ay1) * 0.5;
          double ww = ax2 - ax1, hh = ay2 - ay1;
          double ctrx = (double)row[0] * ww + cx;
          double ctry = (double)row[1] * hh + cy;
          double szx = fast_exp_d((double)row[2]) * ww;
          double szy = fast_exp_d((double)row[3]) * hh;
          double* bp = boxesd + (size_t)(b * Nn + n) * 4;
          bp[0] = clip01(ctrx - szx * 0.5);
          bp[1] = clip01(ctry - szy * 0.5);
          bp[2] = clip01(ctrx + szx * 0.5);
          bp[3] = clip01(ctry + szy * 0.5);
          clsd[b * Nn + n] = ai;
          u64 sb2 = (u64)__double_as_longlong(score);
          u64 e4 = (sb2 >> 52) - 1015ULL;
          u64 mant45 = (sb2 & ((1ULL << 52) - 1)) >> 7;
          u64 flip = (~((e4 << 45) | mant45)) & ((1ULL << 49) - 1);
          K = (flip << 15) | (u64)n;
        }
      }
    }
    if (s == 0) ekseg[pass * 64 + g] = K;
  }
  __syncthreads();

  for (int k = 2; k <= 256; k <<= 1) {
    for (int j = k >> 1; j >= 1; j >>= 1) {
      if (tid < 128) {
        int l = ((tid & ~(j - 1)) << 1) | (tid & (j - 1));
        int r = l | j;
        bool up = ((l & k) == 0);
        u64 a = ekseg[l], bv = ekseg[r];
        if ((a > bv) == up) { ekseg[l] = bv; ekseg[r] = a; }
      }
      __syncthreads();
    }
  }
  u64* dstp = ekeysG + (size_t)b * CHPRE + c * CH + seg * 256;
  for (int i = tid; i < 256; i += 256) dstp[i] = ekseg[i];
}

// ============================================================
// z5: per-image: chunk loop {8-way bitonic merge (c<3) or inline
// rescore + full sort (c==3, ~never) -> multi-wave NMS} -> outputs
// (verbatim R15: 64-wide batches, double-buffered box staging)
// ============================================================
__global__ __launch_bounds__(1024) void z5_sortnms(const float* __restrict__ logits,
                                                   const float* __restrict__ anchors,
                                                   const u64* __restrict__ ekeysG,
                                                   const int* __restrict__ chunkCntG,
                                                   const int* __restrict__ clist,
                                                   double* __restrict__ boxesd,
                                                   int* __restrict__ clsd,
                                                   float* __restrict__ out) {
  __shared__ u64 ek[CH];
  __shared__ double bbuf[2][64][4];
  __shared__ u64 awv[16];
  __shared__ u64 killm[64];
  __shared__ double selBox[MAXB][4];
  __shared__ double selArea[MAXB];
  __shared__ float selScore[MAXB];
  __shared__ int selIdx[MAXB];
  __shared__ int sS;
  const int b = blockIdx.x;
  const int tid = threadIdx.x;
  const int lane = tid & 63, wid = tid >> 6;
  const double THR = 0.45;
  if (tid == 0) sS = 0;
  __syncthreads();

  for (int c = 0; c < NCHK; ++c) {
    if (sS >= MAXB) break;
    int cnt = chunkCntG[b * NCHK + c];
    cnt = cnt > CH ? CH : cnt;
    if (cnt == 0) break;

    if (c < CHK_PRE) {
      for (int i = tid; i < CH; i += 1024) ek[i] = ekeysG[(size_t)b * CHPRE + c * CH + i];
      __syncthreads();
      for (int L = 256; L <= 1024; L <<= 1) {
        int pair = tid / L, i = tid % L;
        int base = pair * 2 * L;
        int l = base + i, r = base + 2 * L - 1 - i;
        u64 a = ek[l], bv = ek[r];
        if (a > bv) { ek[l] = bv; ek[r] = a; }
        __syncthreads();
        for (int j = L >> 1; j >= 1; j >>= 1) {
          int ll = ((tid & ~(j - 1)) << 1) | (tid & (j - 1));
          int rr = ll | j;
          u64 x = ek[ll], y = ek[rr];
          if (x > y) { ek[ll] = y; ek[rr] = x; }
          __syncthreads();
        }
      }
    } else {
      for (int i = tid; i < CH; i += 1024) ek[i] = ~0ULL;
      __syncthreads();
      const int g = tid >> 2, s4 = tid & 3;
      #pragma unroll 1
      for (int pass = 0; pass < CH / 256; ++pass) {
        int slot = pass * 256 + g;
        if (slot < cnt) {
          const int n = clist[b * CHTOT + c * CH + slot];
          const float* row = logits + ((size_t)b * Nn + n) * 85;
          float rv[21];
          float mx = -1e30f; int ai = 1000;
          #pragma unroll
          for (int q = 0; q < 21; ++q) {
            int cc = s4 + 4 * q;
            float vv = (cc < 81) ? row[4 + cc] : -1e30f;
            rv[q] = vv;
            if (cc < 81 && vv > mx) { mx = vv; ai = cc; }
          }
          #pragma unroll
          for (int d = 1; d <= 2; d <<= 1) {
            float om = __shfl_xor(mx, d);
            int oi = __shfl_xor(ai, d);
            if (om > mx || (om == mx && oi < ai)) { mx = om; ai = oi; }
          }
          double sum = 0.0;
          #pragma unroll
          for (int q = 0; q < 21; ++q) {
            if (s4 + 4 * q < 81) sum += fast_exp_d((double)rv[q] - (double)mx);
          }
          sum += __shfl_xor(sum, 1);
          sum += __shfl_xor(sum, 2);
          if (s4 == 0) {
            u64 K = ~0ULL;
            double score = 1.0 / sum;
            if (ai != 0 && score >= 0.01) {
              float4 a4 = reinterpret_cast<const float4*>(anchors)[n];
              double ax1 = a4.x, ay1 = a4.y, ax2 = a4.z, ay2 = a4.w;
              double cx = (ax2 + ax1) * 0.5, cy = (ay2 + ay1) * 0.5;
              double ww = ax2 - ax1, hh = ay2 - ay1;
              double ctrx = (double)row[0] * ww + cx;
              double ctry = (double)row[1] * hh + cy;
              double szx = fast_exp_d((double)row[2]) * ww;
              double szy = fast_exp_d((double)row[3]) * hh;
              double* bp = boxesd + (size_t)(b * Nn + n) * 4;
              bp[0] = clip01(ctrx - szx * 0.5);
              bp[1] = clip01(ctry - szy * 0.5);
              bp[2] = clip01(ctrx + szx * 0.5);
              bp[3] = clip01(ctry + szy * 0.5);
              clsd[b * Nn + n] = ai;
              u64 sb2 = (u64)__double_as_longlong(score);
              u64 e4 = (sb2 >> 52) - 1015ULL;
              u64 mant45 = (sb2 & ((1ULL << 52) - 1)) >> 7;
              u64 flip = (~((e4 << 45) | mant45)) & ((1ULL << 49) - 1);
              K = (flip << 15) | (u64)n;
            }
            ek[slot] = K;
          }
        }
      }
      __syncthreads();
      int P2 = 64;
      while (P2 < cnt) P2 <<= 1;
      for (int k = 2; k <= P2; k <<= 1) {
        for (int j = k >> 1; j >= 1; j >>= 1) {
          if (tid < (P2 >> 1)) {
            int l = ((tid & ~(j - 1)) << 1) | (tid & (j - 1));
            int r = l | j;
            bool up = ((l & k) == 0);
            u64 a = ek[l], bbv = ek[r];
            if ((a > bbv) == up) { ek[l] = bbv; ek[r] = a; }
          }
          __syncthreads();
        }
      }
    }

    // ---- multi-wave NMS, parallel kill-masks ----
    int pos = 0, bf = 0;
    if (tid < 256) {
      int ci = tid >> 2, comp = tid & 3;
      u64 Kc = ek[ci];
      double vv = 0.0;
      if (Kc != ~0ULL) vv = boxesd[(size_t)(b * Nn + (int)(Kc & 0x7FFF)) * 4 + comp];
      bbuf[0][ci][comp] = vv;
    }
    __syncthreads();
    for (;;) {
      int S = sS;
      if (S >= MAXB || pos >= CH) break;
      u64 K = ek[pos + lane];
      bool valid = (K != ~0ULL);
      if (!__any(valid)) break;

      if (tid < 256 && pos + 64 < CH) {
        int ci = tid >> 2, comp = tid & 3;
        u64 Kc = ek[pos + 64 + ci];
        double vv = 0.0;
        if (Kc != ~0ULL) vv = boxesd[(size_t)(b * Nn + (int)(Kc & 0x7FFF)) * 4 + comp];
        bbuf[bf ^ 1][ci][comp] = vv;
      }

      double cx1 = bbuf[bf][lane][0], cy1 = bbuf[bf][lane][1];
      double cx2 = bbuf[bf][lane][2], cy2 = bbuf[bf][lane][3];
      double carea = (cx2 - cx1) * (cy2 - cy1);

      bool aliveL = true;
      for (int k = wid; k < S; k += 16) {
        double ltx = fmax(selBox[k][0], cx1), lty = fmax(selBox[k][1], cy1);
        double rbx = fmin(selBox[k][2], cx2), rby = fmin(selBox[k][3], cy2);
        double w = rbx - ltx; w = w < 0 ? 0 : w;
        double h = rby - lty; h = h < 0 ? 0 : h;
        double inter = w * h;
        double denom = selArea[k] + carea - inter + 1e-9;
        if (inter > THR * denom) aliveL = false;
      }
      u64 aw = __ballot(aliveL);
      if (lane == 0) awv[wid] = aw;

      #pragma unroll
      for (int q = 0; q < 4; ++q) {
        int j = (wid << 2) | q;
        double jx1 = bbuf[bf][j][0], jy1 = bbuf[bf][j][1];
        double jx2 = bbuf[bf][j][2], jy2 = bbuf[bf][j][3];
        double jar = (jx2 - jx1) * (jy2 - jy1);
        double ltx = fmax(jx1, cx1), lty = fmax(jy1, cy1);
        double rbx = fmin(jx2, cx2), rby = fmin(jy2, cy2);
        double w = rbx - ltx; w = w < 0 ? 0 : w;
        double h = rby - lty; h = h < 0 ? 0 : h;
        double inter = w * h;
        double denom = jar + carea - inter + 1e-9;
        u64 km = __ballot(inter > THR * denom);
        if (lane == 0) killm[j] = km;
      }
      __syncthreads();

      if (tid < 64) {
        u64 alive = __ballot(valid);
        #pragma unroll
        for (int w = 0; w < 16; ++w) alive &= awv[w];
        u64 m = alive;
        int Sl = S;
        while (m != 0 && Sl < MAXB) {
          int j = __ffsll((unsigned long long)m) - 1;
          if (lane == 0) {
            double jx1 = bbuf[bf][j][0], jy1 = bbuf[bf][j][1];
            double jx2 = bbuf[bf][j][2], jy2 = bbuf[bf][j][3];
            u64 Kj = ek[pos + j];
            u64 key49 = (~(Kj >> 15)) & ((1ULL << 49) - 1);
            u64 e = (key49 >> 45) + 1015ULL;
            u64 mant = (key49 & ((1ULL << 45) - 1)) << 7;
            selBox[Sl][0] = jx1; selBox[Sl][1] = jy1;
            selBox[Sl][2] = jx2; selBox[Sl][3] = jy2;
            selArea[Sl] = (jx2 - jx1) * (jy2 - jy1);
            selScore[Sl] = (float)__longlong_as_double((long long)((e << 52) | mant));
            selIdx[Sl] = (int)(Kj & 0x7FFF);
          }
          Sl++;
          m &= ~(1ULL << j);
          m &= ~killm[j];
        }
        if (lane == 0) sS = Sl;
      }
      __syncthreads();
      bf ^= 1;
      pos += 64;
    }
    __syncthreads();
  }

  // --- outputs (whole buffer read as f32 by harness) ---
  const int S = sS;
  float* det_boxes = out;
  float* det_classes = out + Bn * MAXB * 4;
  float* det_scores = out + Bn * MAXB * 4 + Bn * MAXB;
  float* det_num = out + Bn * MAXB * 4 + 2 * Bn * MAXB;
  for (int k = tid; k < MAXB; k += 1024) {
    int o = b * MAXB + k;
    if (k < S) {
      det_boxes[o * 4 + 0] = (float)selBox[k][0];
      det_boxes[o * 4 + 1] = (float)selBox[k][1];
      det_boxes[o * 4 + 2] = (float)selBox[k][2];
      det_boxes[o * 4 + 3] = (float)selBox[k][3];
      det_classes[o] = (float)clsd[b * Nn + selIdx[k]];
      det_scores[o] = selScore[k];
    } else {
      det_boxes[o * 4 + 0] = 0.f; det_boxes[o * 4 + 1] = 0.f;
      det_boxes[o * 4 + 2] = 0.f; det_boxes[o * 4 + 3] = 0.f;
      det_classes[o] = 0.f;
      det_scores[o] = 0.f;
    }
  }
  if (tid == 0) det_num[b] = (float)S;
}

// ============================================================
extern "C" void kernel_launch(void* const* d_in, const int* in_sizes, int n_in,
                              void* d_out, int out_size, void* d_ws, size_t ws_size,
                              hipStream_t stream) {
  const float* logits = (const float*)d_in[0];
  const float* anchors = (const float*)d_in[1];
  float* out = (float*)d_out;
  char* ws = (char*)d_ws;

  double* boxesd = (double*)ws;
  size_t off = (size_t)Bn * Nn * 4 * sizeof(double);
  int* clsd    = (int*)(ws + off);  off += (size_t)Bn * Nn * sizeof(int);
  u32* keyA    = (u32*)(ws + off);  off += (size_t)Bn * Nn * sizeof(u32);
  int* chunkCnt= (int*)(ws + off);  off += (size_t)Bn * NCHK * sizeof(int);
  int* clist   = (int*)(ws + off);  off += (size_t)Bn * CHTOT * sizeof(int);
  u64* ekeysG  = (u64*)(ws + off);

  z1_score     <<<dim3(Bn * 384),        dim3(256),  0, stream>>>(logits, keyA);
  z3_cutcompact<<<dim3(Bn),              dim3(1024), 0, stream>>>(keyA, chunkCnt, clist);
  z4_rescore   <<<dim3(Bn * CHK_PRE * 8),dim3(256),  0, stream>>>(logits, anchors, clist,
                                                                  chunkCnt, boxesd, clsd, ekeysG);
  z5_sortnms   <<<dim3(Bn),              dim3(1024), 0, stream>>>(logits, anchors, ekeysG,
                                                                  chunkCnt, clist, boxesd,
                                                                  clsd, out);
}